// Round 7
// baseline (179.200 us; speedup 1.0000x reference)
//
#include <hip/hip_runtime.h>

#define BN 2048
#define DD 128

typedef __attribute__((ext_vector_type(8))) short bf8;
typedef __attribute__((ext_vector_type(16))) float f16v;

__device__ __forceinline__ short bf16rne(float f) {
    unsigned u = __float_as_uint(f);
    u = (u + 0x7FFFu + ((u >> 16) & 1u)) >> 16;
    return (short)u;
}

__device__ __forceinline__ unsigned pk2(float a, float b) {
    return ((unsigned)(unsigned short)bf16rne(b) << 16) | (unsigned short)bf16rne(a);
}

__device__ __forceinline__ bf8 cvt8(float4 f0, float4 f1) {
    bf8 w;
    w[0] = bf16rne(f0.x); w[1] = bf16rne(f0.y);
    w[2] = bf16rne(f0.z); w[3] = bf16rne(f0.w);
    w[4] = bf16rne(f1.x); w[5] = bf16rne(f1.y);
    w[6] = bf16rne(f1.z); w[7] = bf16rne(f1.w);
    return w;
}

// ---------------- pre-pass (R3-VERBATIM, known-passing) ---------------------
// K image (b,it): granule o = g*128 + r  (16B) = K[it*128+r][g*8 .. g*8+7]
// V image (b,it): granule o = kg*128 + d (16B) = { V[it*128+kg*8+j][d] } j=0..7
__launch_bounds__(256, 4)
__global__ void prep_kernel(const float* __restrict__ K, const float* __restrict__ V,
                            short* __restrict__ KS, short* __restrict__ VS) {
    __shared__ short tile[128 * 136];   // [r][d], row stride 136 shorts
    const int t = threadIdx.x;
    const int blk = blockIdx.x;
    const bool isK = blk < 256;
    const int bb = isK ? blk : blk - 256;
    const int b = bb >> 4, it = bb & 15;
    const float* src = (isK ? K : V) + ((size_t)b * BN + it * 128) * DD;

    #pragma unroll
    for (int i = 0; i < 8; ++i) {
        int gid = t + 256 * i;
        int r = gid >> 4, g = gid & 15;
        float4 f0 = *(const float4*)(src + r * DD + g * 8);
        float4 f1 = *(const float4*)(src + r * DD + g * 8 + 4);
        *(bf8*)&tile[r * 136 + g * 8] = cvt8(f0, f1);
    }
    __syncthreads();

    if (isK) {
        short* dst = KS + (((size_t)b * 16 + it) << 14);
        #pragma unroll
        for (int i = 0; i < 8; ++i) {
            int o = t + 256 * i;
            int g = o >> 7, r = o & 127;
            *(bf8*)&dst[o * 8] = *(const bf8*)&tile[r * 136 + g * 8];
        }
    } else {
        short* dst = VS + (((size_t)b * 16 + it) << 14);
        #pragma unroll
        for (int i = 0; i < 4; ++i) {
            int p = t + 256 * i;
            int kg = p >> 6;
            int d0 = (p & 63) * 2;
            bf8 w0, w1;
            #pragma unroll
            for (int j = 0; j < 8; ++j) {
                unsigned u = *(const unsigned*)&tile[(kg * 8 + j) * 136 + d0];
                w0[j] = (short)(u & 0xFFFF);
                w1[j] = (short)(u >> 16);
            }
            int o = kg * 128 + d0;
            *(bf8*)&dst[o * 8] = w0;
            *(bf8*)&dst[(o + 1) * 8] = w1;
        }
    }
}

// softmax + build PV A-operand fragments (R3-verbatim)
__device__ __forceinline__ void build_frags(const f16v& s, float scl, float& l,
                                            bf8 af[2], int lh) {
    float pv[16];
    #pragma unroll
    for (int r = 0; r < 16; ++r) {
        pv[r] = __builtin_amdgcn_exp2f(s[r] * scl);
        l += pv[r];
    }
    unsigned P2[8];
    #pragma unroll
    for (int G = 0; G < 4; ++G) {
        P2[G * 2 + 0] = pk2(pv[4 * G + 0], pv[4 * G + 1]);
        P2[G * 2 + 1] = pk2(pv[4 * G + 2], pv[4 * G + 3]);
    }
    #pragma unroll
    for (int s2 = 0; s2 < 2; ++s2) {
        unsigned send0 = lh ? P2[4 * s2 + 0] : P2[4 * s2 + 2];
        unsigned send1 = lh ? P2[4 * s2 + 1] : P2[4 * s2 + 3];
        unsigned r0 = (unsigned)__shfl_xor((int)send0, 32, 64);
        unsigned r1 = (unsigned)__shfl_xor((int)send1, 32, 64);
        unsigned own0 = lh ? P2[4 * s2 + 2] : P2[4 * s2 + 0];
        unsigned own1 = lh ? P2[4 * s2 + 3] : P2[4 * s2 + 1];
        union { unsigned u[4]; bf8 v; } f;
        f.u[0] = lh ? r0 : own0;
        f.u[1] = lh ? r1 : own1;
        f.u[2] = lh ? own0 : r0;
        f.u[3] = lh ? own1 : r1;
        af[s2] = f.v;
    }
}

// ---------------- attention v7: barrier-free main loop ----------------------
// attn3's exact geometry/dataflow (grid 512, 64 q x 2048 keys, 4 key-quarter
// waves, S^T trick, in-kernel division) but K/V fragments are loaded DIRECTLY
// from the prep images into VGPRs — no LDS staging, no __syncthreads in the
// main loop. Each wave reads only its own granules; prep's image order makes
// those reads coalesced b128 loads that hit L1/L2 (per-XCD working set 4 MB).
__launch_bounds__(256, 2)
__global__ void attn7(const float* __restrict__ Q,
                      const short* __restrict__ KS,
                      const short* __restrict__ VS,
                      const int* __restrict__ VL,
                      float* __restrict__ O) {
    __shared__ __align__(16) char smem[32768 + 1024];
    float* buf = (float*)smem;             // [4 waves][64 q][32 d] f32 per phase
    float* lSh = (float*)(smem + 32768);   // [4 waves][64 q]

    const int tid  = threadIdx.x;
    const int wave = tid >> 6;
    const int lane = tid & 63;
    const int lw   = lane & 31;
    const int lh   = lane >> 5;
    const int kq   = wave;        // key quarter of each 128-key tile
    const int kt   = kq * 32;

    const int L  = blockIdx.x;
    const int b  = (L & 7) | (((L >> 3) & 1) << 3);
    const int qt0 = L >> 4;
    const int q0 = qt0 * 64;

    const int vlen = VL[b];
    constexpr float SCL2 = 1.4426950408889634f * 0.08838834764831845f; // log2e/sqrt(128)

    const float scl0 = (q0 + lw      >= vlen) ? 0.0f : SCL2;
    const float scl1 = (q0 + 32 + lw >= vlen) ? 0.0f : SCL2;

    // granule pointers (16 B units): tile it at offset it*2048 granules
    const bf8* kbase = (const bf8*)(KS + (((size_t)b * 16) << 14));
    const bf8* vbase = (const bf8*)(VS + (((size_t)b * 16) << 14));

    // Q fragments, B-layout (R3-verbatim): lane n=q holds d = ks*16 + lh*8 + j
    bf8 qfrag[2][8];
    #pragma unroll
    for (int qt = 0; qt < 2; ++qt) {
        const float* qp = Q + ((size_t)b * BN + q0 + qt * 32 + lw) * DD;
        #pragma unroll
        for (int ks = 0; ks < 8; ++ks) {
            int d0 = ks * 16 + lh * 8;
            float4 f0 = *(const float4*)(qp + d0);
            float4 f1 = *(const float4*)(qp + d0 + 4);
            qfrag[qt][ks] = cvt8(f0, f1);
        }
    }

    f16v oacc[2][4] = {};
    float l0 = 0.0f, l1 = 0.0f;

    for (int it = 0; it < 16; ++it) {
        const bf8* kg = kbase + it * 2048;
        const bf8* vg = vbase + it * 2048;

        // ---- S^T = K Q^T : K frags straight from global (L2-resident image)
        bf8 kf[8];
        #pragma unroll
        for (int ks = 0; ks < 8; ++ks)
            kf[ks] = kg[(ks * 2 + lh) * 128 + kt + lw];
        f16v s0 = {}, s1 = {};
        #pragma unroll
        for (int ks = 0; ks < 8; ++ks) {
            s0 = __builtin_amdgcn_mfma_f32_32x32x16_bf16(kf[ks], qfrag[0][ks], s0, 0, 0, 0);
            s1 = __builtin_amdgcn_mfma_f32_32x32x16_bf16(kf[ks], qfrag[1][ks], s1, 0, 0, 0);
        }

        // ---- softmax + in-register P fragments (R3-verbatim)
        bf8 af0[2], af1[2];
        build_frags(s0, scl0, l0, af0, lh);
        build_frags(s1, scl1, l1, af1, lh);

        // ---- O += P V : V frags straight from global
        #pragma unroll
        for (int s2 = 0; s2 < 2; ++s2) {
            #pragma unroll
            for (int ot = 0; ot < 4; ++ot) {
                const bf8 vf = vg[(kq * 4 + 2 * s2 + lh) * 128 + ot * 32 + lw];
                oacc[0][ot] = __builtin_amdgcn_mfma_f32_32x32x16_bf16(af0[s2], vf, oacc[0][ot], 0, 0, 0);
                oacc[1][ot] = __builtin_amdgcn_mfma_f32_32x32x16_bf16(af1[s2], vf, oacc[1][ot], 0, 0, 0);
            }
        }
    }

    // ---- epilogue: combine 4 key-quarter partials, quarter-phase LDS (32 KB)
    l0 += __shfl_xor(l0, 32, 64);
    l1 += __shfl_xor(l1, 32, 64);
    if (lh == 0) {
        lSh[wave * 64 + lw] = l0;
        lSh[wave * 64 + 32 + lw] = l1;
    }
    const size_t orow0 = (size_t)b * BN + q0;
    #pragma unroll
    for (int ot = 0; ot < 4; ++ot) {
        #pragma unroll
        for (int qt = 0; qt < 2; ++qt) {
            #pragma unroll
            for (int reg = 0; reg < 16; ++reg) {
                int row = (reg & 3) + 8 * (reg >> 2) + 4 * lh;
                buf[wave * 2048 + (qt * 32 + row) * 32 + lw] = oacc[qt][ot][reg];
            }
        }
        __syncthreads();    // buf (and, on first phase, lSh) visible
        #pragma unroll
        for (int i = 0; i < 8; ++i) {
            int idx = tid + 256 * i;         // 0..2047 = [64 q][32 d]
            int q = idx >> 5;
            float ltot = lSh[q] + lSh[64 + q] + lSh[128 + q] + lSh[192 + q];
            float v = buf[idx] + buf[2048 + idx] + buf[4096 + idx] + buf[6144 + idx];
            O[(orow0 + q) * DD + ot * 32 + (idx & 31)] = v * __builtin_amdgcn_rcpf(ltot);
        }
        __syncthreads();    // reads done before next phase overwrites buf
    }
}

// ---------------- fallback (no workspace): correct but slow -----------------
__launch_bounds__(256, 2)
__global__ void attn_fallback(const float* __restrict__ Q,
                              const float* __restrict__ K,
                              const float* __restrict__ V,
                              const int* __restrict__ VL,
                              float* __restrict__ O) {
    const int b = blockIdx.x >> 7;
    const int q = ((blockIdx.x & 127) * 16) + (threadIdx.x >> 4);
    const int dl = (threadIdx.x & 15) * 8;
    const int vlen = VL[b];
    const float scl = (q >= vlen) ? 0.0f : (1.4426950408889634f * 0.08838834764831845f);
    const float* qp = Q + ((size_t)b * BN + q) * DD;
    float acc[8] = {};
    float l = 0.0f;
    for (int k = 0; k < BN; ++k) {
        const float* kp = K + ((size_t)b * BN + k) * DD;
        float s = 0.0f;
        for (int d = 0; d < DD; ++d) s += qp[d] * kp[d];
        float p = __builtin_amdgcn_exp2f(s * scl);
        l += p;
        const float* vp = V + ((size_t)b * BN + k) * DD + dl;
        #pragma unroll
        for (int e = 0; e < 8; ++e) acc[e] += p * vp[e];
    }
    float* op = O + ((size_t)b * BN + q) * DD + dl;
    #pragma unroll
    for (int e = 0; e < 8; ++e) op[e] = acc[e] / l;
}

extern "C" void kernel_launch(void* const* d_in, const int* in_sizes, int n_in,
                              void* d_out, int out_size, void* d_ws, size_t ws_size,
                              hipStream_t stream) {
    const float* Q  = (const float*)d_in[0];
    const float* K  = (const float*)d_in[1];
    const float* V  = (const float*)d_in[2];
    const int*   VL = (const int*)d_in[3];
    float* O = (float*)d_out;

    const size_t ks_elems = (size_t)16 * 16 * 16384;       // 4M shorts = 8 MB each
    const size_t need = 2 * ks_elems * sizeof(short);      // 16 MB
    if (ws_size >= need) {
        short* KS = (short*)d_ws;
        short* VS = KS + ks_elems;
        prep_kernel<<<512, 256, 0, stream>>>(K, V, KS, VS);
        attn7<<<512, 256, 0, stream>>>(Q, KS, VS, VL, O);
    } else {
        attn_fallback<<<2048, 256, 0, stream>>>(Q, K, V, VL, O);
    }
}